// Round 1
// baseline (179.716 us; speedup 1.0000x reference)
//
#include <hip/hip_runtime.h>
#include <math.h>

#define N_PILLARS 100000
#define P_PTS 32
#define BN_EPS 1e-3f

// ws layout:
//   [0, 512)        gsums: s1[64], s2[64]      (memset to 0 each launch)
//   [512, 1024)     sb:    scale[64], bias[64]
//   [1024, ...)     means: float4 per pillar (mx,my,mz,0)  = 1.6 MB

// ---------------------------------------------------------------------------
// Pass A: per-pillar mean (over ALL 32 points, as reference does) + channel
// sums of x and x^2 over VALID points (masked points contribute 0).
// One wave per pillar; lane = output channel.
// ---------------------------------------------------------------------------
__global__ __launch_bounds__(256) void pfn_stats(
    const float* __restrict__ vox,      // [N,32,4]
    const int*   __restrict__ npts,     // [N]
    const float* __restrict__ ctr,      // [N,2]
    const float* __restrict__ W,        // [64,9]
    float*       __restrict__ gsums,    // [128]
    float4*      __restrict__ means)    // [N]
{
    __shared__ float4 sv[4][32];        // per-wave voxel staging
    __shared__ float  red[2][4][64];

    const int tid  = threadIdx.x;
    const int wave = tid >> 6, lane = tid & 63;
    const int o = lane;

    float w[9];
#pragma unroll
    for (int c = 0; c < 9; ++c) w[c] = W[o * 9 + c];
    const float Wc0 = w[0] + w[4] + w[7];
    const float Wc1 = w[1] + w[5] + w[8];
    const float Wc2 = w[2] + w[6];
    const float Wc3 = w[3];

    float s1 = 0.f, s2 = 0.f;
    const int stride = gridDim.x * 4;
    for (int n = blockIdx.x * 4 + wave; n < N_PILLARS; n += stride) {
        // stage all 32 points: each lane loads 8B (coalesced 512B/wave)
        const float2* src = (const float2*)(vox + (size_t)n * 128);
        ((float2*)&sv[wave][lane >> 1])[lane & 1] = src[lane];

        // per-pillar xyz sum over all 32 points (both 32-lane halves duplicate)
        float4 pv = sv[wave][lane & 31];
        float sx = pv.x, sy = pv.y, sz = pv.z;
#pragma unroll
        for (int m = 1; m < 32; m <<= 1) {
            sx += __shfl_xor(sx, m);
            sy += __shfl_xor(sy, m);
            sz += __shfl_xor(sz, m);
        }
        const int   np  = npts[n];
        const float inv = 1.0f / (float)np;
        const float mx = sx * inv, my = sy * inv, mz = sz * inv;
        const float cx = ctr[n * 2 + 0], cyv = ctr[n * 2 + 1];
        // per-(pillar,channel) constant term
        const float t = -(mx * w[4] + my * w[5] + mz * w[6] + cx * w[7] + cyv * w[8]);

        for (int p = 0; p < np; ++p) {
            float4 v = sv[wave][p];              // broadcast ds_read_b128
            float  x = fmaf(v.x, Wc0, t);
            x = fmaf(v.y, Wc1, x);
            x = fmaf(v.z, Wc2, x);
            x = fmaf(v.w, Wc3, x);
            s1 += x;
            s2 = fmaf(x, x, s2);
        }
        if (lane == 0) means[n] = make_float4(mx, my, mz, 0.f);
    }

    red[0][wave][lane] = s1;
    red[1][wave][lane] = s2;
    __syncthreads();
    if (wave == 0) {
        float a = red[0][0][lane] + red[0][1][lane] + red[0][2][lane] + red[0][3][lane];
        float b = red[1][0][lane] + red[1][1][lane] + red[1][2][lane] + red[1][3][lane];
        atomicAdd(&gsums[lane], a);
        atomicAdd(&gsums[64 + lane], b);
    }
}

// ---------------------------------------------------------------------------
// Pass B: fold BN stats into per-channel scale/bias.
// ---------------------------------------------------------------------------
__global__ void pfn_scale(const float* __restrict__ gsums,
                          const float* __restrict__ gamma,
                          const float* __restrict__ beta,
                          float* __restrict__ sb)
{
    int o = threadIdx.x;
    if (o < 64) {
        const float invNP = 1.0f / (float)(N_PILLARS * P_PTS);
        float mean = gsums[o] * invNP;
        float var  = gsums[64 + o] * invNP - mean * mean;
        float sc   = gamma[o] * rsqrtf(var + BN_EPS);
        sb[o]      = sc;
        sb[64 + o] = beta[o] - mean * sc;
    }
}

// ---------------------------------------------------------------------------
// Pass C: per pillar, per channel: running max/min of x over valid points
// (+0 if any masked point), then out = relu(m*scale + bias).
// Loads ONLY valid points; mean comes from ws cache.
// ---------------------------------------------------------------------------
__global__ __launch_bounds__(256) void pfn_final(
    const float*  __restrict__ vox,
    const int*    __restrict__ npts,
    const float*  __restrict__ ctr,
    const float*  __restrict__ W,
    const float4* __restrict__ means,
    const float*  __restrict__ sb,
    float*        __restrict__ out)     // [N,64]
{
    __shared__ float4 sv[4][32];

    const int tid  = threadIdx.x;
    const int wave = tid >> 6, lane = tid & 63;
    const int o = lane;

    const float w4 = W[o * 9 + 4], w5 = W[o * 9 + 5], w6 = W[o * 9 + 6];
    const float w7 = W[o * 9 + 7], w8 = W[o * 9 + 8];
    const float Wc0 = W[o * 9 + 0] + w4 + w7;
    const float Wc1 = W[o * 9 + 1] + w5 + w8;
    const float Wc2 = W[o * 9 + 2] + w6;
    const float Wc3 = W[o * 9 + 3];
    const float sc = sb[o], bs = sb[64 + o];

    const int stride = gridDim.x * 4;
    for (int n = blockIdx.x * 4 + wave; n < N_PILLARS; n += stride) {
        const int np = npts[n];
        const int p  = lane >> 1;
        if (p < np)   // stage only valid points
            ((float2*)&sv[wave][p])[lane & 1] =
                ((const float2*)(vox + (size_t)n * 128))[lane];

        const float4 m  = means[n];
        const float  cx = ctr[n * 2 + 0], cyv = ctr[n * 2 + 1];
        const float  t  = -(m.x * w4 + m.y * w5 + m.z * w6 + cx * w7 + cyv * w8);

        float hi = -INFINITY, lo = INFINITY;
        for (int q = 0; q < np; ++q) {
            float4 v = sv[wave][q];              // broadcast ds_read_b128
            float  x = fmaf(v.x, Wc0, t);
            x = fmaf(v.y, Wc1, x);
            x = fmaf(v.z, Wc2, x);
            x = fmaf(v.w, Wc3, x);
            hi = fmaxf(hi, x);
            lo = fminf(lo, x);
        }
        if (np < P_PTS) { hi = fmaxf(hi, 0.f); lo = fminf(lo, 0.f); }

        const float mm = (sc >= 0.f) ? hi : lo;  // affine is monotone in x
        out[(size_t)n * 64 + o] = fmaxf(0.f, fmaf(mm, sc, bs));
    }
}

extern "C" void kernel_launch(void* const* d_in, const int* in_sizes, int n_in,
                              void* d_out, int out_size, void* d_ws, size_t ws_size,
                              hipStream_t stream) {
    const float* voxels  = (const float*)d_in[0];
    const int*   npts    = (const int*)d_in[1];
    const float* centers = (const float*)d_in[2];
    const float* W       = (const float*)d_in[3];
    const float* gamma   = (const float*)d_in[4];
    const float* beta    = (const float*)d_in[5];
    float* out = (float*)d_out;

    float*  gsums = (float*)d_ws;
    float*  sb    = (float*)d_ws + 128;
    float4* means = (float4*)((char*)d_ws + 1024);

    hipMemsetAsync(d_ws, 0, 512, stream);
    pfn_stats<<<1024, 256, 0, stream>>>(voxels, npts, centers, W, gsums, means);
    pfn_scale<<<1, 64, 0, stream>>>(gsums, gamma, beta, sb);
    pfn_final<<<2048, 256, 0, stream>>>(voxels, npts, centers, W, means, sb, out);
}